// Round 5
// baseline (917.449 us; speedup 1.0000x reference)
//
#include <hip/hip_runtime.h>
#include <math.h>

#define NN  50000
#define FIN 512
#define HH1 500
#define HH2 100
#define NC  16
#define NE  800000

typedef __attribute__((ext_vector_type(4))) float  f32x4;
typedef __attribute__((ext_vector_type(4))) __bf16 bf16x4;
typedef __attribute__((ext_vector_type(8))) __bf16 bf16x8;

// ---------------- CSR build ----------------

__global__ void zero2_k(int* a, int* b) {
    int i = blockIdx.x * blockDim.x + threadIdx.x;
    if (i < NN) { a[i] = 0; b[i] = 0; }
}

__global__ void hist_k(const int* __restrict__ rows, int* __restrict__ rowcnt) {
    int i = blockIdx.x * blockDim.x + threadIdx.x;
    if (i < NE) atomicAdd(&rowcnt[rows[i]], 1);
}

__global__ void dinv_k(const int* __restrict__ rowcnt, float* __restrict__ dinv) {
    int i = blockIdx.x * blockDim.x + threadIdx.x;
    if (i < NN) dinv[i] = rsqrtf((float)(rowcnt[i] + 1));   // +1 self-loop
}

__global__ __launch_bounds__(1024) void scan_k(const int* __restrict__ cnt,
                                               int* __restrict__ ptr) {
    __shared__ int s[1024];
    __shared__ int carry;
    int t = threadIdx.x;
    if (t == 0) carry = 0;
    __syncthreads();
    for (int base = 0; base < NN; base += 1024) {
        int i = base + t;
        int v = (i < NN) ? cnt[i] : 0;
        s[t] = v;
        __syncthreads();
        #pragma unroll
        for (int off = 1; off < 1024; off <<= 1) {
            int add = (t >= off) ? s[t - off] : 0;
            __syncthreads();
            s[t] += add;
            __syncthreads();
        }
        int excl = s[t] - v;
        if (i < NN) ptr[i] = carry + excl;
        __syncthreads();
        if (t == 1023) carry += s[1023];
        __syncthreads();
    }
}

__global__ void scatter_k(const int* __restrict__ rows, const int* __restrict__ cols,
                          const float* __restrict__ dinv,
                          const int* __restrict__ row_ptr, int* __restrict__ fill,
                          int* __restrict__ col_s, float* __restrict__ w_s) {
    int e = blockIdx.x * blockDim.x + threadIdx.x;
    if (e >= NE) return;
    int r = rows[e], c = cols[e];
    int pos = row_ptr[r] + atomicAdd(&fill[r], 1);
    col_s[pos] = c;
    w_s[pos] = dinv[r] * dinv[c];
}

// ---------------- W pre-transpose + bf16 hi/lo split ----------------

__global__ void wsplit_k(const float* __restrict__ W, __bf16* __restrict__ Wth,
                         __bf16* __restrict__ Wtl, int k, int m)
{
    int idx = blockIdx.x * 256 + threadIdx.x;
    int n_ = idx >> 9;
    int kk = idx & 511;
    float v = (kk < k && n_ < m) ? W[(size_t)kk * m + n_] : 0.0f;
    __bf16 h = (__bf16)v;
    Wth[idx] = h;
    Wtl[idx] = (__bf16)(v - (float)h);
}

// ---------------- MFMA GEMM (bf16 hi/lo split, fp32-grade) ----------------

__global__ __launch_bounds__(256) void gemm_mfma_k(
    const float* __restrict__ A, const __bf16* __restrict__ Wth,
    const __bf16* __restrict__ Wtl, const float* __restrict__ bias,
    float* __restrict__ C, int n, int kdim, int m)
{
    __shared__ __align__(16) __bf16 Ahi[128 * 32];
    __shared__ __align__(16) __bf16 Alo[128 * 32];
    __shared__ __align__(16) __bf16 Bhi[128 * 32];
    __shared__ __align__(16) __bf16 Blo[128 * 32];

    int tid  = threadIdx.x;
    int lane = tid & 63;
    int wid  = tid >> 6;
    int wrow = wid & 1, wcol = wid >> 1;
    int lr = lane & 15, q = lane >> 4;
    int row0 = blockIdx.x * 128, col0 = blockIdx.y * 128;

    f32x4 zero = {0.f, 0.f, 0.f, 0.f};
    f32x4 acc[4][4];
    #pragma unroll
    for (int i = 0; i < 4; i++)
        #pragma unroll
        for (int j = 0; j < 4; j++) acc[i][j] = zero;

    for (int kt = 0; kt < kdim; kt += 32) {
        #pragma unroll
        for (int i = 0; i < 4; i++) {
            int idx = tid + i * 256;
            int rr = idx >> 3, c4 = idx & 7;
            int gr = row0 + rr, gk = kt + c4 * 4;
            float4 v = make_float4(0.f, 0.f, 0.f, 0.f);
            if (gr < n && gk < kdim) v = *(const float4*)(A + (size_t)gr * kdim + gk);
            __bf16 h0 = (__bf16)v.x, h1 = (__bf16)v.y, h2 = (__bf16)v.z, h3 = (__bf16)v.w;
            bf16x4 hv = {h0, h1, h2, h3};
            bf16x4 lv = {(__bf16)(v.x - (float)h0), (__bf16)(v.y - (float)h1),
                         (__bf16)(v.z - (float)h2), (__bf16)(v.w - (float)h3)};
            *(bf16x4*)(Ahi + rr * 32 + c4 * 4) = hv;
            *(bf16x4*)(Alo + rr * 32 + c4 * 4) = lv;
        }
        #pragma unroll
        for (int i = 0; i < 2; i++) {
            int idx = tid + i * 256;
            int rr = idx >> 2, c8 = idx & 3;
            size_t goff = (size_t)(col0 + rr) * 512 + kt + c8 * 8;
            *(bf16x8*)(Bhi + rr * 32 + c8 * 8) = *(const bf16x8*)(Wth + goff);
            *(bf16x8*)(Blo + rr * 32 + c8 * 8) = *(const bf16x8*)(Wtl + goff);
        }
        __syncthreads();

        bf16x8 ah[4], al[4], bh[4], bl[4];
        #pragma unroll
        for (int t = 0; t < 4; t++) {
            int aoff = (wrow * 64 + t * 16 + lr) * 32 + q * 8;
            ah[t] = *(const bf16x8*)(Ahi + aoff);
            al[t] = *(const bf16x8*)(Alo + aoff);
            int boff = (wcol * 64 + t * 16 + lr) * 32 + q * 8;
            bh[t] = *(const bf16x8*)(Bhi + boff);
            bl[t] = *(const bf16x8*)(Blo + boff);
        }
        #pragma unroll
        for (int ti = 0; ti < 4; ti++)
            #pragma unroll
            for (int tj = 0; tj < 4; tj++) {
                acc[ti][tj] = __builtin_amdgcn_mfma_f32_16x16x32_bf16(
                    al[ti], bh[tj], acc[ti][tj], 0, 0, 0);
                acc[ti][tj] = __builtin_amdgcn_mfma_f32_16x16x32_bf16(
                    ah[ti], bl[tj], acc[ti][tj], 0, 0, 0);
                acc[ti][tj] = __builtin_amdgcn_mfma_f32_16x16x32_bf16(
                    ah[ti], bh[tj], acc[ti][tj], 0, 0, 0);
            }
        __syncthreads();
    }

    #pragma unroll
    for (int ti = 0; ti < 4; ti++) {
        #pragma unroll
        for (int tj = 0; tj < 4; tj++) {
            int col = col0 + wcol * 64 + tj * 16 + lr;
            if (col >= m) continue;
            float bv = bias[col];
            #pragma unroll
            for (int p = 0; p < 4; p++) {
                int row = row0 + wrow * 64 + ti * 16 + q * 4 + p;
                if (row < n) C[(size_t)row * m + col] = acc[ti][tj][p] + bv;
            }
        }
    }
}

// ---------------- small GEMM (layer 3): 64x64 tile fp32 ----------------

#define BM 64
#define BN 64
#define BK 16

__global__ __launch_bounds__(256) void gemm_bias_k(
    const float* __restrict__ A, const float* __restrict__ W,
    const float* __restrict__ bias, float* __restrict__ C,
    int n, int k, int m)
{
    __shared__ float As[BK][BM + 1];
    __shared__ float Ws[BK][BN];

    int tid = threadIdx.x;
    int tx = tid & 15;
    int ty = tid >> 4;
    int row0 = blockIdx.x * BM;
    int col0 = blockIdx.y * BN;

    float acc[4][4] = {};

    for (int kt = 0; kt < k; kt += BK) {
        #pragma unroll
        for (int i = 0; i < 4; i++) {
            int idx = tid + i * 256;
            int r  = idx >> 4;
            int kk = idx & 15;
            int gr = row0 + r, gk = kt + kk;
            As[kk][r] = (gr < n && gk < k) ? A[(size_t)gr * k + gk] : 0.0f;
        }
        #pragma unroll
        for (int i = 0; i < 4; i++) {
            int idx = tid + i * 256;
            int kk = idx >> 6;
            int c  = idx & 63;
            int gk = kt + kk, gc = col0 + c;
            Ws[kk][c] = (gk < k && gc < m) ? W[(size_t)gk * m + gc] : 0.0f;
        }
        __syncthreads();

        #pragma unroll
        for (int kk = 0; kk < BK; kk++) {
            float a[4], w[4];
            #pragma unroll
            for (int i = 0; i < 4; i++) a[i] = As[kk][ty * 4 + i];
            #pragma unroll
            for (int j = 0; j < 4; j++) w[j] = Ws[kk][tx * 4 + j];
            #pragma unroll
            for (int i = 0; i < 4; i++)
                #pragma unroll
                for (int j = 0; j < 4; j++)
                    acc[i][j] += a[i] * w[j];
        }
        __syncthreads();
    }

    #pragma unroll
    for (int i = 0; i < 4; i++) {
        int gr = row0 + ty * 4 + i;
        if (gr >= n) continue;
        #pragma unroll
        for (int j = 0; j < 4; j++) {
            int gc = col0 + tx * 4 + j;
            if (gc < m) C[(size_t)gr * m + gc] = acc[i][j] + bias[gc];
        }
    }
}

// ---------------- SpMM L1 (500-wide): 1 wave/row, 2 vecs/lane, 4-edge unroll ----
// out[r,:] = tanh( dinv[r]^2*h[r,:] + sum_j w_j * h[col_j,:] )

__global__ __launch_bounds__(256) void spmm500_k(
    const int* __restrict__ row_ptr, const int* __restrict__ rowcnt,
    const int* __restrict__ col_s, const float* __restrict__ w_s,
    const float* __restrict__ dinv, const float* __restrict__ h,
    float* __restrict__ out)
{
    int r = blockIdx.x * 4 + (threadIdx.x >> 6);
    int lane = threadIdx.x & 63;
    if (r >= NN) return;
    bool a1 = lane < (125 - 64);    // second vec active for lanes 0..60

    const f32x4* h4 = (const f32x4*)h;   // row stride = 125 f32x4
    f32x4* o4 = (f32x4*)out;

    float d = dinv[r];
    float sw = d * d;
    size_t rbase = (size_t)r * 125;
    f32x4 acc0 = sw * h4[rbase + lane];
    f32x4 acc1 = {0.f, 0.f, 0.f, 0.f};
    if (a1) acc1 = sw * h4[rbase + 64 + lane];

    int beg = row_ptr[r], cnt = rowcnt[r];
    int j = 0;
    for (; j + 3 < cnt; j += 4) {
        int   c0 = col_s[beg + j],     c1 = col_s[beg + j + 1];
        int   c2 = col_s[beg + j + 2], c3 = col_s[beg + j + 3];
        float w0 = w_s[beg + j],       w1 = w_s[beg + j + 1];
        float w2 = w_s[beg + j + 2],   w3 = w_s[beg + j + 3];
        size_t b0 = (size_t)c0 * 125, b1 = (size_t)c1 * 125;
        size_t b2 = (size_t)c2 * 125, b3 = (size_t)c3 * 125;
        // issue all 8 vector loads, then FMA
        f32x4 p0 = h4[b0 + lane];
        f32x4 p1 = h4[b1 + lane];
        f32x4 p2 = h4[b2 + lane];
        f32x4 p3 = h4[b3 + lane];
        f32x4 q0 = {0,0,0,0}, q1 = {0,0,0,0}, q2 = {0,0,0,0}, q3 = {0,0,0,0};
        if (a1) {
            q0 = h4[b0 + 64 + lane];
            q1 = h4[b1 + 64 + lane];
            q2 = h4[b2 + 64 + lane];
            q3 = h4[b3 + 64 + lane];
        }
        acc0 += w0 * p0; acc0 += w1 * p1; acc0 += w2 * p2; acc0 += w3 * p3;
        acc1 += w0 * q0; acc1 += w1 * q1; acc1 += w2 * q2; acc1 += w3 * q3;
    }
    for (; j < cnt; j++) {
        int   c0 = col_s[beg + j];
        float w0 = w_s[beg + j];
        size_t b0 = (size_t)c0 * 125;
        acc0 += w0 * h4[b0 + lane];
        if (a1) acc1 += w0 * h4[b0 + 64 + lane];
    }

    f32x4 t0, t1;
    t0.x = tanhf(acc0.x); t0.y = tanhf(acc0.y); t0.z = tanhf(acc0.z); t0.w = tanhf(acc0.w);
    __builtin_nontemporal_store(t0, &o4[rbase + lane]);
    if (a1) {
        t1.x = tanhf(acc1.x); t1.y = tanhf(acc1.y); t1.z = tanhf(acc1.z); t1.w = tanhf(acc1.w);
        __builtin_nontemporal_store(t1, &o4[rbase + 64 + lane]);
    }
}

// ---------------- generic CSR SpMM (layers 2/3), 4-edge unroll ----------------

template<int TPR, int NV, int ACT>
__global__ __launch_bounds__(256) void spmm_csr_k(
    const int* __restrict__ row_ptr, const int* __restrict__ rowcnt,
    const int* __restrict__ col_s, const float* __restrict__ w_s,
    const float* __restrict__ dinv, const float* __restrict__ h,
    float* __restrict__ out)
{
    const int rpb = 256 / TPR;
    int r = blockIdx.x * rpb + threadIdx.x / TPR;
    int lane = threadIdx.x % TPR;
    if (r >= NN) return;
    bool active = lane < NV;

    const f32x4* h4 = (const f32x4*)h;
    f32x4* o4 = (f32x4*)out;

    float d = dinv[r];
    f32x4 acc = {0.f, 0.f, 0.f, 0.f};
    if (active) acc = (d * d) * h4[(size_t)r * NV + lane];

    int beg = row_ptr[r], cnt = rowcnt[r];
    int j = 0;
    for (; j + 3 < cnt; j += 4) {
        int   c0 = col_s[beg + j],     c1 = col_s[beg + j + 1];
        int   c2 = col_s[beg + j + 2], c3 = col_s[beg + j + 3];
        float w0 = w_s[beg + j],       w1 = w_s[beg + j + 1];
        float w2 = w_s[beg + j + 2],   w3 = w_s[beg + j + 3];
        if (active) {
            f32x4 v0 = h4[(size_t)c0 * NV + lane];
            f32x4 v1 = h4[(size_t)c1 * NV + lane];
            f32x4 v2 = h4[(size_t)c2 * NV + lane];
            f32x4 v3 = h4[(size_t)c3 * NV + lane];
            acc += w0 * v0; acc += w1 * v1; acc += w2 * v2; acc += w3 * v3;
        }
    }
    for (; j < cnt; j++) {
        int   c0 = col_s[beg + j];
        float w0 = w_s[beg + j];
        if (active) acc += w0 * h4[(size_t)c0 * NV + lane];
    }

    if (active) {
        if (ACT == 1) {
            acc.x = tanhf(acc.x); acc.y = tanhf(acc.y);
            acc.z = tanhf(acc.z); acc.w = tanhf(acc.w);
        }
        __builtin_nontemporal_store(acc, &o4[(size_t)r * NV + lane]);
    }
}

// final: tanh then softmax over 16 classes, one thread per row
__global__ void tanh_softmax_k(const float* __restrict__ in, float* __restrict__ out) {
    int r = blockIdx.x * blockDim.x + threadIdx.x;
    if (r >= NN) return;
    float v[NC];
    float mx = -1e30f;
    #pragma unroll
    for (int j = 0; j < NC; j++) {
        v[j] = tanhf(in[r * NC + j]);
        mx = fmaxf(mx, v[j]);
    }
    float s = 0.0f;
    #pragma unroll
    for (int j = 0; j < NC; j++) { v[j] = expf(v[j] - mx); s += v[j]; }
    float inv = 1.0f / s;
    #pragma unroll
    for (int j = 0; j < NC; j++) out[r * NC + j] = v[j] * inv;
}

// ---------------- launch ----------------

extern "C" void kernel_launch(void* const* d_in, const int* in_sizes, int n_in,
                              void* d_out, int out_size, void* d_ws, size_t ws_size,
                              hipStream_t stream)
{
    const float* x  = (const float*)d_in[0];
    const int*   ei = (const int*)d_in[1];
    const float* W1 = (const float*)d_in[2];
    const float* b1 = (const float*)d_in[3];
    const float* W2 = (const float*)d_in[4];
    const float* b2 = (const float*)d_in[5];
    const float* W3 = (const float*)d_in[6];
    const float* b3 = (const float*)d_in[7];
    float* out = (float*)d_out;

    const int* rows = ei;
    const int* cols = ei + NE;

    char* p = (char*)d_ws;
    float*  dinv    = (float*)p;   p += (size_t)NN * 4;
    int*    rowcnt  = (int*)p;     p += (size_t)NN * 4;
    int*    row_ptr = (int*)p;     p += (size_t)NN * 4;
    int*    fill    = (int*)p;     p += (size_t)NN * 4;
    int*    col_s   = (int*)p;     p += (size_t)NE * 4;
    float*  w_s     = (float*)p;   p += (size_t)NE * 4;
    float*  A       = (float*)p;   p += (size_t)NN * HH1 * 4;
    float*  B       = (float*)p;   p += (size_t)NN * HH1 * 4;
    __bf16* Wth1    = (__bf16*)p;  p += (size_t)512 * 512 * 2;
    __bf16* Wtl1    = (__bf16*)p;  p += (size_t)512 * 512 * 2;
    __bf16* Wth2    = (__bf16*)p;  p += (size_t)128 * 512 * 2;
    __bf16* Wtl2    = (__bf16*)p;  p += (size_t)128 * 512 * 2;

    const int T = 256;

    zero2_k<<<(NN + T - 1) / T, T, 0, stream>>>(rowcnt, fill);
    hist_k<<<(NE + T - 1) / T, T, 0, stream>>>(rows, rowcnt);
    dinv_k<<<(NN + T - 1) / T, T, 0, stream>>>(rowcnt, dinv);
    scan_k<<<1, 1024, 0, stream>>>(rowcnt, row_ptr);
    scatter_k<<<(NE + T - 1) / T, T, 0, stream>>>(rows, cols, dinv, row_ptr, fill,
                                                  col_s, w_s);
    wsplit_k<<<512 * 512 / 256, T, 0, stream>>>(W1, Wth1, Wtl1, FIN, HH1);
    wsplit_k<<<128 * 512 / 256, T, 0, stream>>>(W2, Wth2, Wtl2, HH1, HH2);

    // ---- layer 1: 512 -> 500
    {
        dim3 g((NN + 127) / 128, (HH1 + 127) / 128);
        gemm_mfma_k<<<g, T, 0, stream>>>(x, Wth1, Wtl1, b1, A, NN, FIN, HH1);
        spmm500_k<<<(NN + 3) / 4, T, 0, stream>>>(row_ptr, rowcnt, col_s, w_s,
                                                  dinv, A, B);
    }
    // ---- layer 2: 500 -> 100
    {
        dim3 g((NN + 127) / 128, 1);
        gemm_mfma_k<<<g, T, 0, stream>>>(B, Wth2, Wtl2, b2, A, NN, HH1, HH2);
        spmm_csr_k<32, 25, 1><<<(NN + 7) / 8, T, 0, stream>>>(
            row_ptr, rowcnt, col_s, w_s, dinv, A, B);
    }
    // ---- layer 3: 100 -> 16
    {
        dim3 g((NN + BM - 1) / BM, (NC + BN - 1) / BN);
        gemm_bias_k<<<g, T, 0, stream>>>(B, W3, b3, A, NN, HH2, NC);
        spmm_csr_k<4, 4, 0><<<(NN + 63) / 64, T, 0, stream>>>(
            row_ptr, rowcnt, col_s, w_s, dinv, A, B);
        tanh_softmax_k<<<(NN + T - 1) / T, T, 0, stream>>>(B, out);
    }
}

// Round 6
// 789.284 us; speedup vs baseline: 1.1624x; 1.1624x over previous
//
#include <hip/hip_runtime.h>
#include <math.h>

#define NN  50000
#define FIN 512
#define HH1 500
#define HH2 100
#define NC  16
#define NE  800000

typedef __attribute__((ext_vector_type(4))) float  f32x4;
typedef __attribute__((ext_vector_type(4))) __bf16 bf16x4;
typedef __attribute__((ext_vector_type(8))) __bf16 bf16x8;
typedef __attribute__((ext_vector_type(8))) unsigned short u16x8;

// ---------------- CSR build ----------------

__global__ void zero2_k(int* a, int* b) {
    int i = blockIdx.x * blockDim.x + threadIdx.x;
    if (i < NN) { a[i] = 0; b[i] = 0; }
}

__global__ void hist_k(const int* __restrict__ rows, int* __restrict__ rowcnt) {
    int i = blockIdx.x * blockDim.x + threadIdx.x;
    if (i < NE) atomicAdd(&rowcnt[rows[i]], 1);
}

__global__ void dinv_k(const int* __restrict__ rowcnt, float* __restrict__ dinv) {
    int i = blockIdx.x * blockDim.x + threadIdx.x;
    if (i < NN) dinv[i] = rsqrtf((float)(rowcnt[i] + 1));   // +1 self-loop
}

__global__ __launch_bounds__(1024) void scan_k(const int* __restrict__ cnt,
                                               int* __restrict__ ptr) {
    __shared__ int s[1024];
    __shared__ int carry;
    int t = threadIdx.x;
    if (t == 0) carry = 0;
    __syncthreads();
    for (int base = 0; base < NN; base += 1024) {
        int i = base + t;
        int v = (i < NN) ? cnt[i] : 0;
        s[t] = v;
        __syncthreads();
        #pragma unroll
        for (int off = 1; off < 1024; off <<= 1) {
            int add = (t >= off) ? s[t - off] : 0;
            __syncthreads();
            s[t] += add;
            __syncthreads();
        }
        int excl = s[t] - v;
        if (i < NN) ptr[i] = carry + excl;
        __syncthreads();
        if (t == 1023) carry += s[1023];
        __syncthreads();
    }
}

__global__ void scatter_k(const int* __restrict__ rows, const int* __restrict__ cols,
                          const float* __restrict__ dinv,
                          const int* __restrict__ row_ptr, int* __restrict__ fill,
                          int* __restrict__ col_s, float* __restrict__ w_s) {
    int e = blockIdx.x * blockDim.x + threadIdx.x;
    if (e >= NE) return;
    int r = rows[e], c = cols[e];
    int pos = row_ptr[r] + atomicAdd(&fill[r], 1);
    col_s[pos] = c;
    w_s[pos] = dinv[r] * dinv[c];
}

// ---------------- W pre-transpose + bf16 hi/lo split ----------------

__global__ void wsplit_k(const float* __restrict__ W, __bf16* __restrict__ Wth,
                         __bf16* __restrict__ Wtl, int k, int m)
{
    int idx = blockIdx.x * 256 + threadIdx.x;
    int n_ = idx >> 9;
    int kk = idx & 511;
    float v = (kk < k && n_ < m) ? W[(size_t)kk * m + n_] : 0.0f;
    __bf16 h = (__bf16)v;
    Wth[idx] = h;
    Wtl[idx] = (__bf16)(v - (float)h);
}

// ---------------- MFMA GEMM (bf16 hi/lo split) -> bf16 output, padded ------

__global__ __launch_bounds__(256) void gemm_mfma_k(
    const float* __restrict__ A, const __bf16* __restrict__ Wth,
    const __bf16* __restrict__ Wtl, const float* __restrict__ bias,
    __bf16* __restrict__ Cb, int mpad,
    int n, int kdim, int m)
{
    __shared__ __align__(16) __bf16 Ahi[128 * 32];
    __shared__ __align__(16) __bf16 Alo[128 * 32];
    __shared__ __align__(16) __bf16 Bhi[128 * 32];
    __shared__ __align__(16) __bf16 Blo[128 * 32];

    int tid  = threadIdx.x;
    int lane = tid & 63;
    int wid  = tid >> 6;
    int wrow = wid & 1, wcol = wid >> 1;
    int lr = lane & 15, q = lane >> 4;
    int row0 = blockIdx.x * 128, col0 = blockIdx.y * 128;

    f32x4 zero = {0.f, 0.f, 0.f, 0.f};
    f32x4 acc[4][4];
    #pragma unroll
    for (int i = 0; i < 4; i++)
        #pragma unroll
        for (int j = 0; j < 4; j++) acc[i][j] = zero;

    for (int kt = 0; kt < kdim; kt += 32) {
        #pragma unroll
        for (int i = 0; i < 4; i++) {
            int idx = tid + i * 256;
            int rr = idx >> 3, c4 = idx & 7;
            int gr = row0 + rr, gk = kt + c4 * 4;
            float4 v = make_float4(0.f, 0.f, 0.f, 0.f);
            if (gr < n && gk < kdim) v = *(const float4*)(A + (size_t)gr * kdim + gk);
            __bf16 h0 = (__bf16)v.x, h1 = (__bf16)v.y, h2 = (__bf16)v.z, h3 = (__bf16)v.w;
            bf16x4 hv = {h0, h1, h2, h3};
            bf16x4 lv = {(__bf16)(v.x - (float)h0), (__bf16)(v.y - (float)h1),
                         (__bf16)(v.z - (float)h2), (__bf16)(v.w - (float)h3)};
            *(bf16x4*)(Ahi + rr * 32 + c4 * 4) = hv;
            *(bf16x4*)(Alo + rr * 32 + c4 * 4) = lv;
        }
        #pragma unroll
        for (int i = 0; i < 2; i++) {
            int idx = tid + i * 256;
            int rr = idx >> 2, c8 = idx & 3;
            size_t goff = (size_t)(col0 + rr) * 512 + kt + c8 * 8;
            *(bf16x8*)(Bhi + rr * 32 + c8 * 8) = *(const bf16x8*)(Wth + goff);
            *(bf16x8*)(Blo + rr * 32 + c8 * 8) = *(const bf16x8*)(Wtl + goff);
        }
        __syncthreads();

        bf16x8 ah[4], al[4], bh[4], bl[4];
        #pragma unroll
        for (int t = 0; t < 4; t++) {
            int aoff = (wrow * 64 + t * 16 + lr) * 32 + q * 8;
            ah[t] = *(const bf16x8*)(Ahi + aoff);
            al[t] = *(const bf16x8*)(Alo + aoff);
            int boff = (wcol * 64 + t * 16 + lr) * 32 + q * 8;
            bh[t] = *(const bf16x8*)(Bhi + boff);
            bl[t] = *(const bf16x8*)(Blo + boff);
        }
        #pragma unroll
        for (int ti = 0; ti < 4; ti++)
            #pragma unroll
            for (int tj = 0; tj < 4; tj++) {
                acc[ti][tj] = __builtin_amdgcn_mfma_f32_16x16x32_bf16(
                    al[ti], bh[tj], acc[ti][tj], 0, 0, 0);
                acc[ti][tj] = __builtin_amdgcn_mfma_f32_16x16x32_bf16(
                    ah[ti], bl[tj], acc[ti][tj], 0, 0, 0);
                acc[ti][tj] = __builtin_amdgcn_mfma_f32_16x16x32_bf16(
                    ah[ti], bh[tj], acc[ti][tj], 0, 0, 0);
            }
        __syncthreads();
    }

    // epilogue: bf16 store, zero-fill pad cols [m, mpad)
    #pragma unroll
    for (int ti = 0; ti < 4; ti++) {
        #pragma unroll
        for (int tj = 0; tj < 4; tj++) {
            int col = col0 + wcol * 64 + tj * 16 + lr;
            if (col >= mpad) continue;
            bool valid = col < m;
            float bv = valid ? bias[col] : 0.0f;
            #pragma unroll
            for (int p = 0; p < 4; p++) {
                int row = row0 + wrow * 64 + ti * 16 + q * 4 + p;
                if (row < n) {
                    float v = valid ? (acc[ti][tj][p] + bv) : 0.0f;
                    Cb[(size_t)row * mpad + col] = (__bf16)v;
                }
            }
        }
    }
}

// ---------------- small GEMM (layer 3): 64x64 tile fp32 ----------------

#define BM 64
#define BN 64
#define BK 16

__global__ __launch_bounds__(256) void gemm_bias_k(
    const float* __restrict__ A, const float* __restrict__ W,
    const float* __restrict__ bias, float* __restrict__ C,
    int n, int k, int m)
{
    __shared__ float As[BK][BM + 1];
    __shared__ float Ws[BK][BN];

    int tid = threadIdx.x;
    int tx = tid & 15;
    int ty = tid >> 4;
    int row0 = blockIdx.x * BM;
    int col0 = blockIdx.y * BN;

    float acc[4][4] = {};

    for (int kt = 0; kt < k; kt += BK) {
        #pragma unroll
        for (int i = 0; i < 4; i++) {
            int idx = tid + i * 256;
            int r  = idx >> 4;
            int kk = idx & 15;
            int gr = row0 + r, gk = kt + kk;
            As[kk][r] = (gr < n && gk < k) ? A[(size_t)gr * k + gk] : 0.0f;
        }
        #pragma unroll
        for (int i = 0; i < 4; i++) {
            int idx = tid + i * 256;
            int kk = idx >> 6;
            int c  = idx & 63;
            int gk = kt + kk, gc = col0 + c;
            Ws[kk][c] = (gk < k && gc < m) ? W[(size_t)gk * m + gc] : 0.0f;
        }
        __syncthreads();

        #pragma unroll
        for (int kk = 0; kk < BK; kk++) {
            float a[4], w[4];
            #pragma unroll
            for (int i = 0; i < 4; i++) a[i] = As[kk][ty * 4 + i];
            #pragma unroll
            for (int j = 0; j < 4; j++) w[j] = Ws[kk][tx * 4 + j];
            #pragma unroll
            for (int i = 0; i < 4; i++)
                #pragma unroll
                for (int j = 0; j < 4; j++)
                    acc[i][j] += a[i] * w[j];
        }
        __syncthreads();
    }

    #pragma unroll
    for (int i = 0; i < 4; i++) {
        int gr = row0 + ty * 4 + i;
        if (gr >= n) continue;
        #pragma unroll
        for (int j = 0; j < 4; j++) {
            int gc = col0 + tx * 4 + j;
            if (gc < m) C[(size_t)gr * m + gc] = acc[i][j] + bias[gc];
        }
    }
}

// ---------------- bf16 FMA helper ----------------

__device__ inline void fma_bf8(f32x4& a0, f32x4& a1, u16x8 v, float w) {
    union U { unsigned u; float f; };
    #pragma unroll
    for (int i = 0; i < 4; i++) { U t; t.u = ((unsigned)v[i]) << 16;     a0[i] += w * t.f; }
    #pragma unroll
    for (int i = 0; i < 4; i++) { U t; t.u = ((unsigned)v[4 + i]) << 16; a1[i] += w * t.f; }
}

// ---------------- SpMM L1: bf16 gather (stride 512), fp32 out (stride 500) ---
// 1 wave/row, lane covers feats [lane*8, lane*8+8). Fused self-loop + tanh.

__global__ __launch_bounds__(256) void spmm_b16_500_k(
    const int* __restrict__ row_ptr, const int* __restrict__ rowcnt,
    const int* __restrict__ col_s, const float* __restrict__ w_s,
    const float* __restrict__ dinv, const __bf16* __restrict__ hb,
    float* __restrict__ out)
{
    int r = blockIdx.x * 4 + (threadIdx.x >> 6);
    int lane = threadIdx.x & 63;
    if (r >= NN) return;

    const u16x8* h8 = (const u16x8*)hb;   // row stride = 64 vec8

    float d = dinv[r];
    f32x4 acc0 = {0.f, 0.f, 0.f, 0.f}, acc1 = {0.f, 0.f, 0.f, 0.f};
    fma_bf8(acc0, acc1, h8[(size_t)r * 64 + lane], d * d);

    int beg = row_ptr[r], cnt = rowcnt[r];
    int j = 0;
    for (; j + 3 < cnt; j += 4) {
        int   c0 = col_s[beg + j],     c1 = col_s[beg + j + 1];
        int   c2 = col_s[beg + j + 2], c3 = col_s[beg + j + 3];
        float w0 = w_s[beg + j],       w1 = w_s[beg + j + 1];
        float w2 = w_s[beg + j + 2],   w3 = w_s[beg + j + 3];
        u16x8 v0 = h8[(size_t)c0 * 64 + lane];
        u16x8 v1 = h8[(size_t)c1 * 64 + lane];
        u16x8 v2 = h8[(size_t)c2 * 64 + lane];
        u16x8 v3 = h8[(size_t)c3 * 64 + lane];
        fma_bf8(acc0, acc1, v0, w0);
        fma_bf8(acc0, acc1, v1, w1);
        fma_bf8(acc0, acc1, v2, w2);
        fma_bf8(acc0, acc1, v3, w3);
    }
    for (; j < cnt; j++) {
        int   c0 = col_s[beg + j];
        float w0 = w_s[beg + j];
        fma_bf8(acc0, acc1, h8[(size_t)c0 * 64 + lane], w0);
    }

    int f0 = lane * 8;
    f32x4 t0, t1;
    #pragma unroll
    for (int i = 0; i < 4; i++) { t0[i] = tanhf(acc0[i]); t1[i] = tanhf(acc1[i]); }
    if (f0 + 4 <= HH1)
        __builtin_nontemporal_store(t0, (f32x4*)(out + (size_t)r * HH1 + f0));
    if (f0 + 8 <= HH1)
        __builtin_nontemporal_store(t1, (f32x4*)(out + (size_t)r * HH1 + f0 + 4));
}

// ---------------- SpMM L2: bf16 gather (stride 128), fp32 out (stride 100) ---
// 16 lanes/row, 16 rows per 256-block.

__global__ __launch_bounds__(256) void spmm_b16_100_k(
    const int* __restrict__ row_ptr, const int* __restrict__ rowcnt,
    const int* __restrict__ col_s, const float* __restrict__ w_s,
    const float* __restrict__ dinv, const __bf16* __restrict__ hb,
    float* __restrict__ out)
{
    int r = blockIdx.x * 16 + (threadIdx.x >> 4);
    int lane = threadIdx.x & 15;
    if (r >= NN) return;

    const u16x8* h8 = (const u16x8*)hb;   // row stride = 16 vec8

    float d = dinv[r];
    f32x4 acc0 = {0.f, 0.f, 0.f, 0.f}, acc1 = {0.f, 0.f, 0.f, 0.f};
    fma_bf8(acc0, acc1, h8[(size_t)r * 16 + lane], d * d);

    int beg = row_ptr[r], cnt = rowcnt[r];
    int j = 0;
    for (; j + 3 < cnt; j += 4) {
        int   c0 = col_s[beg + j],     c1 = col_s[beg + j + 1];
        int   c2 = col_s[beg + j + 2], c3 = col_s[beg + j + 3];
        float w0 = w_s[beg + j],       w1 = w_s[beg + j + 1];
        float w2 = w_s[beg + j + 2],   w3 = w_s[beg + j + 3];
        u16x8 v0 = h8[(size_t)c0 * 16 + lane];
        u16x8 v1 = h8[(size_t)c1 * 16 + lane];
        u16x8 v2 = h8[(size_t)c2 * 16 + lane];
        u16x8 v3 = h8[(size_t)c3 * 16 + lane];
        fma_bf8(acc0, acc1, v0, w0);
        fma_bf8(acc0, acc1, v1, w1);
        fma_bf8(acc0, acc1, v2, w2);
        fma_bf8(acc0, acc1, v3, w3);
    }
    for (; j < cnt; j++) {
        int   c0 = col_s[beg + j];
        float w0 = w_s[beg + j];
        fma_bf8(acc0, acc1, h8[(size_t)c0 * 16 + lane], w0);
    }

    int f0 = lane * 8;
    f32x4 t0, t1;
    #pragma unroll
    for (int i = 0; i < 4; i++) { t0[i] = tanhf(acc0[i]); t1[i] = tanhf(acc1[i]); }
    if (f0 + 4 <= HH2)
        __builtin_nontemporal_store(t0, (f32x4*)(out + (size_t)r * HH2 + f0));
    if (f0 + 8 <= HH2)
        __builtin_nontemporal_store(t1, (f32x4*)(out + (size_t)r * HH2 + f0 + 4));
}

// ---------------- fp32 CSR SpMM (layer 3, 16-wide) ----------------

template<int TPR, int NV, int ACT>
__global__ __launch_bounds__(256) void spmm_csr_k(
    const int* __restrict__ row_ptr, const int* __restrict__ rowcnt,
    const int* __restrict__ col_s, const float* __restrict__ w_s,
    const float* __restrict__ dinv, const float* __restrict__ h,
    float* __restrict__ out)
{
    const int rpb = 256 / TPR;
    int r = blockIdx.x * rpb + threadIdx.x / TPR;
    int lane = threadIdx.x % TPR;
    if (r >= NN) return;
    bool active = lane < NV;

    const f32x4* h4 = (const f32x4*)h;
    f32x4* o4 = (f32x4*)out;

    float d = dinv[r];
    f32x4 acc = {0.f, 0.f, 0.f, 0.f};
    if (active) acc = (d * d) * h4[(size_t)r * NV + lane];

    int beg = row_ptr[r], cnt = rowcnt[r];
    int j = 0;
    for (; j + 3 < cnt; j += 4) {
        int   c0 = col_s[beg + j],     c1 = col_s[beg + j + 1];
        int   c2 = col_s[beg + j + 2], c3 = col_s[beg + j + 3];
        float w0 = w_s[beg + j],       w1 = w_s[beg + j + 1];
        float w2 = w_s[beg + j + 2],   w3 = w_s[beg + j + 3];
        if (active) {
            f32x4 v0 = h4[(size_t)c0 * NV + lane];
            f32x4 v1 = h4[(size_t)c1 * NV + lane];
            f32x4 v2 = h4[(size_t)c2 * NV + lane];
            f32x4 v3 = h4[(size_t)c3 * NV + lane];
            acc += w0 * v0; acc += w1 * v1; acc += w2 * v2; acc += w3 * v3;
        }
    }
    for (; j < cnt; j++) {
        int   c0 = col_s[beg + j];
        float w0 = w_s[beg + j];
        if (active) acc += w0 * h4[(size_t)c0 * NV + lane];
    }

    if (active) {
        if (ACT == 1) {
            acc.x = tanhf(acc.x); acc.y = tanhf(acc.y);
            acc.z = tanhf(acc.z); acc.w = tanhf(acc.w);
        }
        __builtin_nontemporal_store(acc, &o4[(size_t)r * NV + lane]);
    }
}

// final: tanh then softmax over 16 classes, one thread per row
__global__ void tanh_softmax_k(const float* __restrict__ in, float* __restrict__ out) {
    int r = blockIdx.x * blockDim.x + threadIdx.x;
    if (r >= NN) return;
    float v[NC];
    float mx = -1e30f;
    #pragma unroll
    for (int j = 0; j < NC; j++) {
        v[j] = tanhf(in[r * NC + j]);
        mx = fmaxf(mx, v[j]);
    }
    float s = 0.0f;
    #pragma unroll
    for (int j = 0; j < NC; j++) { v[j] = expf(v[j] - mx); s += v[j]; }
    float inv = 1.0f / s;
    #pragma unroll
    for (int j = 0; j < NC; j++) out[r * NC + j] = v[j] * inv;
}

// ---------------- launch ----------------

extern "C" void kernel_launch(void* const* d_in, const int* in_sizes, int n_in,
                              void* d_out, int out_size, void* d_ws, size_t ws_size,
                              hipStream_t stream)
{
    const float* x  = (const float*)d_in[0];
    const int*   ei = (const int*)d_in[1];
    const float* W1 = (const float*)d_in[2];
    const float* b1 = (const float*)d_in[3];
    const float* W2 = (const float*)d_in[4];
    const float* b2 = (const float*)d_in[5];
    const float* W3 = (const float*)d_in[6];
    const float* b3 = (const float*)d_in[7];
    float* out = (float*)d_out;

    const int* rows = ei;
    const int* cols = ei + NE;

    char* p = (char*)d_ws;
    float*  dinv    = (float*)p;   p += (size_t)NN * 4;
    int*    rowcnt  = (int*)p;     p += (size_t)NN * 4;
    int*    row_ptr = (int*)p;     p += (size_t)NN * 4;
    int*    fill    = (int*)p;     p += (size_t)NN * 4;
    int*    col_s   = (int*)p;     p += (size_t)NE * 4;
    float*  w_s     = (float*)p;   p += (size_t)NE * 4;
    float*  h1      = (float*)p;   p += (size_t)NN * HH1 * 4;   // SpMM1 out / GEMM2 in
    float*  h2      = (float*)p;   p += (size_t)NN * HH2 * 4;   // SpMM2 out / GEMM3 in
    float*  A3      = (float*)p;   p += (size_t)NN * NC * 4;    // GEMM3 out
    float*  B3      = (float*)p;   p += (size_t)NN * NC * 4;    // SpMM3 out
    __bf16* A1b     = (__bf16*)p;  p += (size_t)NN * 512 * 2;   // GEMM1 out (padded)
    __bf16* A2b     = (__bf16*)p;  p += (size_t)NN * 128 * 2;   // GEMM2 out (padded)
    __bf16* Wth1    = (__bf16*)p;  p += (size_t)512 * 512 * 2;
    __bf16* Wtl1    = (__bf16*)p;  p += (size_t)512 * 512 * 2;
    __bf16* Wth2    = (__bf16*)p;  p += (size_t)128 * 512 * 2;
    __bf16* Wtl2    = (__bf16*)p;  p += (size_t)128 * 512 * 2;

    const int T = 256;

    zero2_k<<<(NN + T - 1) / T, T, 0, stream>>>(rowcnt, fill);
    hist_k<<<(NE + T - 1) / T, T, 0, stream>>>(rows, rowcnt);
    dinv_k<<<(NN + T - 1) / T, T, 0, stream>>>(rowcnt, dinv);
    scan_k<<<1, 1024, 0, stream>>>(rowcnt, row_ptr);
    scatter_k<<<(NE + T - 1) / T, T, 0, stream>>>(rows, cols, dinv, row_ptr, fill,
                                                  col_s, w_s);
    wsplit_k<<<512 * 512 / 256, T, 0, stream>>>(W1, Wth1, Wtl1, FIN, HH1);
    wsplit_k<<<128 * 512 / 256, T, 0, stream>>>(W2, Wth2, Wtl2, HH1, HH2);

    // ---- layer 1: 512 -> 500
    {
        dim3 g((NN + 127) / 128, 512 / 128);
        gemm_mfma_k<<<g, T, 0, stream>>>(x, Wth1, Wtl1, b1, A1b, 512, NN, FIN, HH1);
        spmm_b16_500_k<<<(NN + 3) / 4, T, 0, stream>>>(row_ptr, rowcnt, col_s, w_s,
                                                       dinv, A1b, h1);
    }
    // ---- layer 2: 500 -> 100
    {
        dim3 g((NN + 127) / 128, 1);
        gemm_mfma_k<<<g, T, 0, stream>>>(h1, Wth2, Wtl2, b2, A2b, 128, NN, HH1, HH2);
        spmm_b16_100_k<<<(NN + 15) / 16, T, 0, stream>>>(row_ptr, rowcnt, col_s, w_s,
                                                         dinv, A2b, h2);
    }
    // ---- layer 3: 100 -> 16
    {
        dim3 g((NN + BM - 1) / BM, (NC + BN - 1) / BN);
        gemm_bias_k<<<g, T, 0, stream>>>(h2, W3, b3, A3, NN, HH2, NC);
        spmm_csr_k<4, 4, 0><<<(NN + 63) / 64, T, 0, stream>>>(
            row_ptr, rowcnt, col_s, w_s, dinv, A3, B3);
        tanh_softmax_k<<<(NN + T - 1) / T, T, 0, stream>>>(B3, out);
    }
}

// Round 7
// 643.793 us; speedup vs baseline: 1.4251x; 1.2260x over previous
//
#include <hip/hip_runtime.h>
#include <math.h>

#define NN  50000
#define FIN 512
#define HH1 500
#define HH2 100
#define NC  16
#define NE  800000
#define KD  512            // padded K for both MFMA GEMMs
#define LDP 40             // LDS row stride in fp16 (80 B: 16B-aligned, non-pow2)

typedef __attribute__((ext_vector_type(4))) float    f32x4;
typedef __attribute__((ext_vector_type(4))) _Float16 f16x4;
typedef __attribute__((ext_vector_type(8))) _Float16 f16x8;
typedef __attribute__((ext_vector_type(8))) unsigned short u16x8;

// ---------------- CSR build ----------------

__global__ void zero2_k(int* a, int* b) {
    int i = blockIdx.x * blockDim.x + threadIdx.x;
    if (i < NN) { a[i] = 0; b[i] = 0; }
}

__global__ void hist_k(const int* __restrict__ rows, int* __restrict__ rowcnt) {
    int i = blockIdx.x * blockDim.x + threadIdx.x;
    if (i < NE) atomicAdd(&rowcnt[rows[i]], 1);
}

__global__ void dinv_k(const int* __restrict__ rowcnt, float* __restrict__ dinv) {
    int i = blockIdx.x * blockDim.x + threadIdx.x;
    if (i < NN) dinv[i] = rsqrtf((float)(rowcnt[i] + 1));   // +1 self-loop
}

__global__ __launch_bounds__(1024) void scan_k(const int* __restrict__ cnt,
                                               int* __restrict__ ptr) {
    __shared__ int s[1024];
    __shared__ int carry;
    int t = threadIdx.x;
    if (t == 0) carry = 0;
    __syncthreads();
    for (int base = 0; base < NN; base += 1024) {
        int i = base + t;
        int v = (i < NN) ? cnt[i] : 0;
        s[t] = v;
        __syncthreads();
        #pragma unroll
        for (int off = 1; off < 1024; off <<= 1) {
            int add = (t >= off) ? s[t - off] : 0;
            __syncthreads();
            s[t] += add;
            __syncthreads();
        }
        int excl = s[t] - v;
        if (i < NN) ptr[i] = carry + excl;
        __syncthreads();
        if (t == 1023) carry += s[1023];
        __syncthreads();
    }
}

__global__ void scatter_k(const int* __restrict__ rows, const int* __restrict__ cols,
                          const float* __restrict__ dinv,
                          const int* __restrict__ row_ptr, int* __restrict__ fill,
                          int* __restrict__ col_s, float* __restrict__ w_s) {
    int e = blockIdx.x * blockDim.x + threadIdx.x;
    if (e >= NE) return;
    int r = rows[e], c = cols[e];
    int pos = row_ptr[r] + atomicAdd(&fill[r], 1);
    col_s[pos] = c;
    w_s[pos] = dinv[r] * dinv[c];
}

// ---------------- W pre-transpose to fp16: Wt[npad][512] ----------------

__global__ void wconv_k(const float* __restrict__ W, _Float16* __restrict__ Wt,
                        int k, int m)
{
    int idx = blockIdx.x * 256 + threadIdx.x;   // covers npad*512
    int n_ = idx >> 9;
    int kk = idx & 511;
    float v = (kk < k && n_ < m) ? W[(size_t)kk * m + n_] : 0.0f;
    Wt[idx] = (_Float16)v;
}

// ---------------- fp16 MFMA GEMM, register-prefetch pipeline ----------------
// C[n,m] = A[n,k] @ W[k,m] + b. 128x128 tile, BK=32, 4 waves x (64x64 quad,
// 4x4 MFMA 16x16x32_f16). A is fp32 (AF16=0, row stride KD) or fp16 (AF16=1,
// row stride KD). K fixed = KD = 512 (16 steps). Output fp16, padded to mpad.

template<int AF16>
__global__ __launch_bounds__(256) void gemm_f16_k(
    const void* __restrict__ Av, const _Float16* __restrict__ Wt,
    const float* __restrict__ bias, _Float16* __restrict__ Cb,
    int mpad, int n, int m)
{
    __shared__ __align__(16) _Float16 As[128 * LDP];
    __shared__ __align__(16) _Float16 Bs[128 * LDP];

    const float*    Af32 = (const float*)Av;
    const _Float16* Af16 = (const _Float16*)Av;

    int tid  = threadIdx.x;
    int lane = tid & 63;
    int wid  = tid >> 6;
    int wrow = wid & 1, wcol = wid >> 1;
    int lr = lane & 15, q = lane >> 4;
    int row0 = blockIdx.x * 128, col0 = blockIdx.y * 128;

    f32x4 acc[4][4];
    #pragma unroll
    for (int i = 0; i < 4; i++)
        #pragma unroll
        for (int j = 0; j < 4; j++) acc[i][j] = (f32x4){0.f, 0.f, 0.f, 0.f};

    // prefetch registers
    float4 pa32[4];
    u16x8  pa16[2];
    u16x8  pb[2];

    // ---- load tile kt into pf regs
    auto load_pf = [&](int kt) {
        if (AF16 == 0) {
            #pragma unroll
            for (int i = 0; i < 4; i++) {
                int idx = tid + i * 256;            // 1024 float4 chunks
                int rr = idx >> 3, c4 = idx & 7;
                int gr = row0 + rr;
                pa32[i] = (gr < n) ? *(const float4*)(Af32 + (size_t)gr * KD + kt + c4 * 4)
                                   : make_float4(0.f, 0.f, 0.f, 0.f);
            }
        } else {
            #pragma unroll
            for (int i = 0; i < 2; i++) {
                int idx = tid + i * 256;            // 512 u16x8 chunks
                int rr = idx >> 2, c8 = idx & 3;
                int gr = row0 + rr;
                pa16[i] = (gr < n) ? *(const u16x8*)(Af16 + (size_t)gr * KD + kt + c8 * 8)
                                   : (u16x8){0, 0, 0, 0, 0, 0, 0, 0};
            }
        }
        #pragma unroll
        for (int i = 0; i < 2; i++) {
            int idx = tid + i * 256;
            int rr = idx >> 2, c8 = idx & 3;
            pb[i] = *(const u16x8*)(Wt + (size_t)(col0 + rr) * KD + kt + c8 * 8);
        }
    };

    load_pf(0);

    for (int step = 0; step < KD / 32; step++) {
        __syncthreads();                 // previous step's LDS readers done
        // ---- store prefetched tile to LDS
        if (AF16 == 0) {
            #pragma unroll
            for (int i = 0; i < 4; i++) {
                int idx = tid + i * 256;
                int rr = idx >> 3, c4 = idx & 7;
                float4 v = pa32[i];
                f16x4 hv = {(_Float16)v.x, (_Float16)v.y, (_Float16)v.z, (_Float16)v.w};
                *(f16x4*)(As + rr * LDP + c4 * 4) = hv;
            }
        } else {
            #pragma unroll
            for (int i = 0; i < 2; i++) {
                int idx = tid + i * 256;
                int rr = idx >> 2, c8 = idx & 3;
                *(u16x8*)(As + rr * LDP + c8 * 8) = pa16[i];
            }
        }
        #pragma unroll
        for (int i = 0; i < 2; i++) {
            int idx = tid + i * 256;
            int rr = idx >> 2, c8 = idx & 3;
            *(u16x8*)(Bs + rr * LDP + c8 * 8) = pb[i];
        }
        __syncthreads();                 // LDS tile visible

        if (step + 1 < KD / 32) load_pf((step + 1) * 32);   // hide latency under MFMA

        // ---- compute
        f16x8 a[4], b[4];
        #pragma unroll
        for (int t = 0; t < 4; t++) {
            a[t] = *(const f16x8*)(As + (wrow * 64 + t * 16 + lr) * LDP + q * 8);
            b[t] = *(const f16x8*)(Bs + (wcol * 64 + t * 16 + lr) * LDP + q * 8);
        }
        #pragma unroll
        for (int ti = 0; ti < 4; ti++)
            #pragma unroll
            for (int tj = 0; tj < 4; tj++)
                acc[ti][tj] = __builtin_amdgcn_mfma_f32_16x16x32_f16(
                    a[ti], b[tj], acc[ti][tj], 0, 0, 0);
    }

    // ---- epilogue: fp16 store, zero pad cols [m, mpad)
    #pragma unroll
    for (int ti = 0; ti < 4; ti++) {
        #pragma unroll
        for (int tj = 0; tj < 4; tj++) {
            int col = col0 + wcol * 64 + tj * 16 + lr;
            if (col >= mpad) continue;
            bool valid = col < m;
            float bv = valid ? bias[col] : 0.0f;
            #pragma unroll
            for (int p = 0; p < 4; p++) {
                int row = row0 + wrow * 64 + ti * 16 + q * 4 + p;
                if (row < n) {
                    float v = valid ? (acc[ti][tj][p] + bv) : 0.0f;
                    Cb[(size_t)row * mpad + col] = (_Float16)v;
                }
            }
        }
    }
}

// ---------------- small GEMM (layer 3): 64x64 tile fp32 ----------------

#define BM 64
#define BN 64
#define BK 16

__global__ __launch_bounds__(256) void gemm_bias_k(
    const float* __restrict__ A, const float* __restrict__ W,
    const float* __restrict__ bias, float* __restrict__ C,
    int n, int k, int m)
{
    __shared__ float As[BK][BM + 1];
    __shared__ float Ws[BK][BN];

    int tid = threadIdx.x;
    int tx = tid & 15;
    int ty = tid >> 4;
    int row0 = blockIdx.x * BM;
    int col0 = blockIdx.y * BN;

    float acc[4][4] = {};

    for (int kt = 0; kt < k; kt += BK) {
        #pragma unroll
        for (int i = 0; i < 4; i++) {
            int idx = tid + i * 256;
            int r  = idx >> 4;
            int kk = idx & 15;
            int gr = row0 + r, gk = kt + kk;
            As[kk][r] = (gr < n && gk < k) ? A[(size_t)gr * k + gk] : 0.0f;
        }
        #pragma unroll
        for (int i = 0; i < 4; i++) {
            int idx = tid + i * 256;
            int kk = idx >> 6;
            int c  = idx & 63;
            int gk = kt + kk, gc = col0 + c;
            Ws[kk][c] = (gk < k && gc < m) ? W[(size_t)gk * m + gc] : 0.0f;
        }
        __syncthreads();

        #pragma unroll
        for (int kk = 0; kk < BK; kk++) {
            float a[4], w[4];
            #pragma unroll
            for (int i = 0; i < 4; i++) a[i] = As[kk][ty * 4 + i];
            #pragma unroll
            for (int j = 0; j < 4; j++) w[j] = Ws[kk][tx * 4 + j];
            #pragma unroll
            for (int i = 0; i < 4; i++)
                #pragma unroll
                for (int j = 0; j < 4; j++)
                    acc[i][j] += a[i] * w[j];
        }
        __syncthreads();
    }

    #pragma unroll
    for (int i = 0; i < 4; i++) {
        int gr = row0 + ty * 4 + i;
        if (gr >= n) continue;
        #pragma unroll
        for (int j = 0; j < 4; j++) {
            int gc = col0 + tx * 4 + j;
            if (gc < m) C[(size_t)gr * m + gc] = acc[i][j] + bias[gc];
        }
    }
}

// ---------------- fp16 helpers ----------------

__device__ __forceinline__ float h2f(unsigned short u) {
    union { unsigned short s; _Float16 f; } t; t.s = u; return (float)t.f;
}

__device__ __forceinline__ void fma_h8(f32x4& a0, f32x4& a1, u16x8 v, float w) {
    #pragma unroll
    for (int i = 0; i < 4; i++) a0[i] += w * h2f(v[i]);
    #pragma unroll
    for (int i = 0; i < 4; i++) a1[i] += w * h2f(v[4 + i]);
}

// ---------------- SpMM L1: fp16 gather (stride 512) -> fp16 out (stride 512) --
// 1 wave/row, lane covers feats [lane*8, lane*8+8). Fused self-loop + tanh.

__global__ __launch_bounds__(256) void spmm_f16_500_k(
    const int* __restrict__ row_ptr, const int* __restrict__ rowcnt,
    const int* __restrict__ col_s, const float* __restrict__ w_s,
    const float* __restrict__ dinv, const _Float16* __restrict__ hb,
    _Float16* __restrict__ outh)
{
    int r = blockIdx.x * 4 + (threadIdx.x >> 6);
    int lane = threadIdx.x & 63;
    if (r >= NN) return;

    const u16x8* h8 = (const u16x8*)hb;   // row stride = 64 vec8

    float d = dinv[r];
    f32x4 acc0 = {0.f, 0.f, 0.f, 0.f}, acc1 = {0.f, 0.f, 0.f, 0.f};
    fma_h8(acc0, acc1, h8[(size_t)r * 64 + lane], d * d);

    int beg = row_ptr[r], cnt = rowcnt[r];
    int j = 0;
    for (; j + 3 < cnt; j += 4) {
        int   c0 = col_s[beg + j],     c1 = col_s[beg + j + 1];
        int   c2 = col_s[beg + j + 2], c3 = col_s[beg + j + 3];
        float w0 = w_s[beg + j],       w1 = w_s[beg + j + 1];
        float w2 = w_s[beg + j + 2],   w3 = w_s[beg + j + 3];
        u16x8 v0 = h8[(size_t)c0 * 64 + lane];
        u16x8 v1 = h8[(size_t)c1 * 64 + lane];
        u16x8 v2 = h8[(size_t)c2 * 64 + lane];
        u16x8 v3 = h8[(size_t)c3 * 64 + lane];
        fma_h8(acc0, acc1, v0, w0);
        fma_h8(acc0, acc1, v1, w1);
        fma_h8(acc0, acc1, v2, w2);
        fma_h8(acc0, acc1, v3, w3);
    }
    for (; j < cnt; j++) {
        fma_h8(acc0, acc1, h8[(size_t)col_s[beg + j] * 64 + lane], w_s[beg + j]);
    }

    int f0 = lane * 8;
    f16x8 o;
    #pragma unroll
    for (int i = 0; i < 4; i++)
        o[i] = (_Float16)((f0 + i < HH1) ? tanhf(acc0[i]) : 0.0f);
    #pragma unroll
    for (int i = 0; i < 4; i++)
        o[4 + i] = (_Float16)((f0 + 4 + i < HH1) ? tanhf(acc1[i]) : 0.0f);
    __builtin_nontemporal_store(o, (f16x8*)(outh + (size_t)r * KD + f0));
}

// ---------------- SpMM L2: fp16 gather (stride 128) -> fp32 out (stride 100) --
// 16 lanes/row, fused self-loop + tanh.

__global__ __launch_bounds__(256) void spmm_f16_100_k(
    const int* __restrict__ row_ptr, const int* __restrict__ rowcnt,
    const int* __restrict__ col_s, const float* __restrict__ w_s,
    const float* __restrict__ dinv, const _Float16* __restrict__ hb,
    float* __restrict__ out)
{
    int r = blockIdx.x * 16 + (threadIdx.x >> 4);
    int lane = threadIdx.x & 15;
    if (r >= NN) return;

    const u16x8* h8 = (const u16x8*)hb;   // row stride = 16 vec8

    float d = dinv[r];
    f32x4 acc0 = {0.f, 0.f, 0.f, 0.f}, acc1 = {0.f, 0.f, 0.f, 0.f};
    fma_h8(acc0, acc1, h8[(size_t)r * 16 + lane], d * d);

    int beg = row_ptr[r], cnt = rowcnt[r];
    int j = 0;
    for (; j + 3 < cnt; j += 4) {
        int   c0 = col_s[beg + j],     c1 = col_s[beg + j + 1];
        int   c2 = col_s[beg + j + 2], c3 = col_s[beg + j + 3];
        float w0 = w_s[beg + j],       w1 = w_s[beg + j + 1];
        float w2 = w_s[beg + j + 2],   w3 = w_s[beg + j + 3];
        u16x8 v0 = h8[(size_t)c0 * 16 + lane];
        u16x8 v1 = h8[(size_t)c1 * 16 + lane];
        u16x8 v2 = h8[(size_t)c2 * 16 + lane];
        u16x8 v3 = h8[(size_t)c3 * 16 + lane];
        fma_h8(acc0, acc1, v0, w0);
        fma_h8(acc0, acc1, v1, w1);
        fma_h8(acc0, acc1, v2, w2);
        fma_h8(acc0, acc1, v3, w3);
    }
    for (; j < cnt; j++) {
        fma_h8(acc0, acc1, h8[(size_t)col_s[beg + j] * 16 + lane], w_s[beg + j]);
    }

    int f0 = lane * 8;
    f32x4 t0, t1;
    #pragma unroll
    for (int i = 0; i < 4; i++) { t0[i] = tanhf(acc0[i]); t1[i] = tanhf(acc1[i]); }
    if (f0 + 4 <= HH2)
        __builtin_nontemporal_store(t0, (f32x4*)(out + (size_t)r * HH2 + f0));
    if (f0 + 8 <= HH2)
        __builtin_nontemporal_store(t1, (f32x4*)(out + (size_t)r * HH2 + f0 + 4));
}

// ---------------- fp32 CSR SpMM (layer 3, 16-wide) ----------------

template<int TPR, int NV, int ACT>
__global__ __launch_bounds__(256) void spmm_csr_k(
    const int* __restrict__ row_ptr, const int* __restrict__ rowcnt,
    const int* __restrict__ col_s, const float* __restrict__ w_s,
    const float* __restrict__ dinv, const float* __restrict__ h,
    float* __restrict__ out)
{
    const int rpb = 256 / TPR;
    int r = blockIdx.x * rpb + threadIdx.x / TPR;
    int lane = threadIdx.x % TPR;
    if (r >= NN) return;
    bool active = lane < NV;

    const f32x4* h4 = (const f32x4*)h;
    f32x4* o4 = (f32x4*)out;

    float d = dinv[r];
    f32x4 acc = {0.f, 0.f, 0.f, 0.f};
    if (active) acc = (d * d) * h4[(size_t)r * NV + lane];

    int beg = row_ptr[r], cnt = rowcnt[r];
    int j = 0;
    for (; j + 3 < cnt; j += 4) {
        int   c0 = col_s[beg + j],     c1 = col_s[beg + j + 1];
        int   c2 = col_s[beg + j + 2], c3 = col_s[beg + j + 3];
        float w0 = w_s[beg + j],       w1 = w_s[beg + j + 1];
        float w2 = w_s[beg + j + 2],   w3 = w_s[beg + j + 3];
        if (active) {
            f32x4 v0 = h4[(size_t)c0 * NV + lane];
            f32x4 v1 = h4[(size_t)c1 * NV + lane];
            f32x4 v2 = h4[(size_t)c2 * NV + lane];
            f32x4 v3 = h4[(size_t)c3 * NV + lane];
            acc += w0 * v0; acc += w1 * v1; acc += w2 * v2; acc += w3 * v3;
        }
    }
    for (; j < cnt; j++) {
        int   c0 = col_s[beg + j];
        float w0 = w_s[beg + j];
        if (active) acc += w0 * h4[(size_t)c0 * NV + lane];
    }

    if (active) {
        if (ACT == 1) {
            acc.x = tanhf(acc.x); acc.y = tanhf(acc.y);
            acc.z = tanhf(acc.z); acc.w = tanhf(acc.w);
        }
        __builtin_nontemporal_store(acc, &o4[(size_t)r * NV + lane]);
    }
}

// final: tanh then softmax over 16 classes, one thread per row
__global__ void tanh_softmax_k(const float* __restrict__ in, float* __restrict__ out) {
    int r = blockIdx.x * blockDim.x + threadIdx.x;
    if (r >= NN) return;
    float v[NC];
    float mx = -1e30f;
    #pragma unroll
    for (int j = 0; j < NC; j++) {
        v[j] = tanhf(in[r * NC + j]);
        mx = fmaxf(mx, v[j]);
    }
    float s = 0.0f;
    #pragma unroll
    for (int j = 0; j < NC; j++) { v[j] = expf(v[j] - mx); s += v[j]; }
    float inv = 1.0f / s;
    #pragma unroll
    for (int j = 0; j < NC; j++) out[r * NC + j] = v[j] * inv;
}

// ---------------- launch ----------------

extern "C" void kernel_launch(void* const* d_in, const int* in_sizes, int n_in,
                              void* d_out, int out_size, void* d_ws, size_t ws_size,
                              hipStream_t stream)
{
    const float* x  = (const float*)d_in[0];
    const int*   ei = (const int*)d_in[1];
    const float* W1 = (const float*)d_in[2];
    const float* b1 = (const float*)d_in[3];
    const float* W2 = (const float*)d_in[4];
    const float* b2 = (const float*)d_in[5];
    const float* W3 = (const float*)d_in[6];
    const float* b3 = (const float*)d_in[7];
    float* out = (float*)d_out;

    const int* rows = ei;
    const int* cols = ei + NE;

    char* p = (char*)d_ws;
    float*     dinv    = (float*)p;     p += (size_t)NN * 4;
    int*       rowcnt  = (int*)p;       p += (size_t)NN * 4;
    int*       row_ptr = (int*)p;       p += (size_t)NN * 4;
    int*       fill    = (int*)p;       p += (size_t)NN * 4;
    int*       col_s   = (int*)p;       p += (size_t)NE * 4;
    float*     w_s     = (float*)p;     p += (size_t)NE * 4;
    float*     h2      = (float*)p;     p += (size_t)NN * HH2 * 4;  // SpMM2 out
    float*     A3      = (float*)p;     p += (size_t)NN * NC * 4;   // GEMM3 out
    float*     B3      = (float*)p;     p += (size_t)NN * NC * 4;   // SpMM3 out
    _Float16*  A1h     = (_Float16*)p;  p += (size_t)NN * KD * 2;   // GEMM1 out (pad 512)
    _Float16*  h1h     = (_Float16*)p;  p += (size_t)NN * KD * 2;   // SpMM1 out (pad 512)
    _Float16*  A2h     = (_Float16*)p;  p += (size_t)NN * 128 * 2;  // GEMM2 out (pad 128)
    _Float16*  Wt1     = (_Float16*)p;  p += (size_t)512 * KD * 2;
    _Float16*  Wt2     = (_Float16*)p;  p += (size_t)128 * KD * 2;

    const int T = 256;

    // ---- preprocessing
    zero2_k<<<(NN + T - 1) / T, T, 0, stream>>>(rowcnt, fill);
    hist_k<<<(NE + T - 1) / T, T, 0, stream>>>(rows, rowcnt);
    dinv_k<<<(NN + T - 1) / T, T, 0, stream>>>(rowcnt, dinv);
    scan_k<<<1, 1024, 0, stream>>>(rowcnt, row_ptr);
    scatter_k<<<(NE + T - 1) / T, T, 0, stream>>>(rows, cols, dinv, row_ptr, fill,
                                                  col_s, w_s);
    wconv_k<<<512 * KD / 256, T, 0, stream>>>(W1, Wt1, FIN, HH1);
    wconv_k<<<128 * KD / 256, T, 0, stream>>>(W2, Wt2, HH1, HH2);

    // ---- layer 1: 512 -> 500 (A = x fp32, K = 512 exact)
    {
        dim3 g((NN + 127) / 128, 4);
        gemm_f16_k<0><<<g, T, 0, stream>>>(x, Wt1, b1, A1h, KD, NN, HH1);
        spmm_f16_500_k<<<(NN + 3) / 4, T, 0, stream>>>(row_ptr, rowcnt, col_s, w_s,
                                                       dinv, A1h, h1h);
    }
    // ---- layer 2: 500 -> 100 (A = h1h fp16 padded to 512)
    {
        dim3 g((NN + 127) / 128, 1);
        gemm_f16_k<1><<<g, T, 0, stream>>>(h1h, Wt2, b2, A2h, 128, NN, HH2);
        spmm_f16_100_k<<<(NN + 15) / 16, T, 0, stream>>>(row_ptr, rowcnt, col_s, w_s,
                                                         dinv, A2h, h2);
    }
    // ---- layer 3: 100 -> 16
    {
        dim3 g((NN + BM - 1) / BM, (NC + BN - 1) / BN);
        gemm_bias_k<<<g, T, 0, stream>>>(h2, W3, b3, A3, NN, HH2, NC);
        spmm_csr_k<4, 4, 0><<<(NN + 63) / 64, T, 0, stream>>>(
            row_ptr, rowcnt, col_s, w_s, dinv, A3, B3);
        tanh_softmax_k<<<(NN + T - 1) / T, T, 0, stream>>>(B3, out);
    }
}

// Round 8
// 565.820 us; speedup vs baseline: 1.6215x; 1.1378x over previous
//
#include <hip/hip_runtime.h>
#include <math.h>

#define NN  50000
#define FIN 512
#define HH1 500
#define HH2 100
#define NC  16
#define NE  800000
#define KD  512            // K-pad for layers 1/2
#define LDP 40             // LDS row stride in fp16 (80 B: 16B-aligned, 2-way banks)

typedef __attribute__((ext_vector_type(4))) float    f32x4;
typedef __attribute__((ext_vector_type(4))) _Float16 f16x4;
typedef __attribute__((ext_vector_type(8))) _Float16 f16x8;
typedef __attribute__((ext_vector_type(8))) unsigned short u16x8;

// ---------------- CSR build ----------------

__global__ void zero2_k(int* a, int* b) {
    int i = blockIdx.x * blockDim.x + threadIdx.x;
    if (i < NN) { a[i] = 0; b[i] = 0; }
}

__global__ void hist_k(const int* __restrict__ rows, int* __restrict__ rowcnt) {
    int i = blockIdx.x * blockDim.x + threadIdx.x;
    if (i < NE) atomicAdd(&rowcnt[rows[i]], 1);
}

__global__ void dinv_k(const int* __restrict__ rowcnt, float* __restrict__ dinv) {
    int i = blockIdx.x * blockDim.x + threadIdx.x;
    if (i < NN) dinv[i] = rsqrtf((float)(rowcnt[i] + 1));   // +1 self-loop
}

// hierarchical scan: 49 blocks x 1024 -> 1-wave scan of block sums -> add
__global__ __launch_bounds__(1024) void scan1_k(const int* __restrict__ cnt,
                                                int* __restrict__ excl,
                                                int* __restrict__ bsum) {
    __shared__ int s[1024];
    int t = threadIdx.x;
    int i = blockIdx.x * 1024 + t;
    int v = (i < NN) ? cnt[i] : 0;
    s[t] = v;
    __syncthreads();
    #pragma unroll
    for (int off = 1; off < 1024; off <<= 1) {
        int add = (t >= off) ? s[t - off] : 0;
        __syncthreads();
        s[t] += add;
        __syncthreads();
    }
    if (i < NN) excl[i] = s[t] - v;
    if (t == 1023) bsum[blockIdx.x] = s[1023];
}

__global__ void scan2_k(int* bsum, int nb) {   // 1 block, 64 threads
    int lane = threadIdx.x;
    int orig = (lane < nb) ? bsum[lane] : 0;
    int v = orig;
    #pragma unroll
    for (int off = 1; off < 64; off <<= 1) {
        int u = __shfl_up(v, off, 64);
        if (lane >= off) v += u;
    }
    if (lane < nb) bsum[lane] = v - orig;      // exclusive
}

__global__ void scan3_k(const int* __restrict__ excl, const int* __restrict__ bsum,
                        int* __restrict__ ptr) {
    int i = blockIdx.x * 256 + threadIdx.x;
    if (i < NN) ptr[i] = excl[i] + bsum[i >> 10];
}

__global__ void scatter_k(const int* __restrict__ rows, const int* __restrict__ cols,
                          const float* __restrict__ dinv,
                          const int* __restrict__ row_ptr, int* __restrict__ fill,
                          int* __restrict__ col_s, float* __restrict__ w_s) {
    int e = blockIdx.x * blockDim.x + threadIdx.x;
    if (e >= NE) return;
    int r = rows[e], c = cols[e];
    int pos = row_ptr[r] + atomicAdd(&fill[r], 1);
    col_s[pos] = c;
    w_s[pos] = dinv[r] * dinv[c];
}

// ---------------- fused W pre-transpose to fp16 ----------------
// Wt1[512][512], Wt2[128][512], Wt3[128][128], zero-padded, n-major.

#define R1 (512 * 512)
#define R2 (128 * 512)
#define R3 (128 * 128)

__global__ void wconv3_k(const float* __restrict__ W1, const float* __restrict__ W2,
                         const float* __restrict__ W3, _Float16* __restrict__ Wt1,
                         _Float16* __restrict__ Wt2, _Float16* __restrict__ Wt3)
{
    int idx = blockIdx.x * 256 + threadIdx.x;
    if (idx < R1) {
        int n_ = idx >> 9, kk = idx & 511;
        float v = (n_ < HH1) ? W1[(size_t)kk * HH1 + n_] : 0.0f;
        Wt1[idx] = (_Float16)v;
    } else if (idx < R1 + R2) {
        int j = idx - R1;
        int n_ = j >> 9, kk = j & 511;
        float v = (kk < HH1 && n_ < HH2) ? W2[(size_t)kk * HH2 + n_] : 0.0f;
        Wt2[j] = (_Float16)v;
    } else if (idx < R1 + R2 + R3) {
        int j = idx - R1 - R2;
        int n_ = j >> 7, kk = j & 127;
        float v = (kk < HH2 && n_ < NC) ? W3[(size_t)kk * NC + n_] : 0.0f;
        Wt3[j] = (_Float16)v;
    }
}

// ---------------- fp16 MFMA GEMM, register-prefetch pipeline ----------------
// C[n,m] = A[n,KDIM] @ Wt^T + b. 128x128 tile, BK=32, 4 waves x 64x64 quad.

template<int AF16, int KDIM>
__global__ __launch_bounds__(256) void gemm_f16_k(
    const void* __restrict__ Av, const _Float16* __restrict__ Wt,
    const float* __restrict__ bias, _Float16* __restrict__ Cb,
    int mpad, int n, int m)
{
    __shared__ __align__(16) _Float16 As[128 * LDP];
    __shared__ __align__(16) _Float16 Bs[128 * LDP];

    const float*    Af32 = (const float*)Av;
    const _Float16* Af16 = (const _Float16*)Av;

    int tid  = threadIdx.x;
    int lane = tid & 63;
    int wid  = tid >> 6;
    int wrow = wid & 1, wcol = wid >> 1;
    int lr = lane & 15, q = lane >> 4;
    int row0 = blockIdx.x * 128, col0 = blockIdx.y * 128;

    f32x4 acc[4][4];
    #pragma unroll
    for (int i = 0; i < 4; i++)
        #pragma unroll
        for (int j = 0; j < 4; j++) acc[i][j] = (f32x4){0.f, 0.f, 0.f, 0.f};

    float4 pa32[4];
    u16x8  pa16[2];
    u16x8  pb[2];

    auto load_pf = [&](int kt) {
        if (AF16 == 0) {
            #pragma unroll
            for (int i = 0; i < 4; i++) {
                int idx = tid + i * 256;
                int rr = idx >> 3, c4 = idx & 7;
                int gr = row0 + rr;
                pa32[i] = (gr < n) ? *(const float4*)(Af32 + (size_t)gr * KDIM + kt + c4 * 4)
                                   : make_float4(0.f, 0.f, 0.f, 0.f);
            }
        } else {
            #pragma unroll
            for (int i = 0; i < 2; i++) {
                int idx = tid + i * 256;
                int rr = idx >> 2, c8 = idx & 3;
                int gr = row0 + rr;
                pa16[i] = (gr < n) ? *(const u16x8*)(Af16 + (size_t)gr * KDIM + kt + c8 * 8)
                                   : (u16x8){0, 0, 0, 0, 0, 0, 0, 0};
            }
        }
        #pragma unroll
        for (int i = 0; i < 2; i++) {
            int idx = tid + i * 256;
            int rr = idx >> 2, c8 = idx & 3;
            pb[i] = *(const u16x8*)(Wt + (size_t)(col0 + rr) * KDIM + kt + c8 * 8);
        }
    };

    load_pf(0);

    for (int step = 0; step < KDIM / 32; step++) {
        __syncthreads();
        if (AF16 == 0) {
            #pragma unroll
            for (int i = 0; i < 4; i++) {
                int idx = tid + i * 256;
                int rr = idx >> 3, c4 = idx & 7;
                float4 v = pa32[i];
                f16x4 hv = {(_Float16)v.x, (_Float16)v.y, (_Float16)v.z, (_Float16)v.w};
                *(f16x4*)(As + rr * LDP + c4 * 4) = hv;
            }
        } else {
            #pragma unroll
            for (int i = 0; i < 2; i++) {
                int idx = tid + i * 256;
                int rr = idx >> 2, c8 = idx & 3;
                *(u16x8*)(As + rr * LDP + c8 * 8) = pa16[i];
            }
        }
        #pragma unroll
        for (int i = 0; i < 2; i++) {
            int idx = tid + i * 256;
            int rr = idx >> 2, c8 = idx & 3;
            *(u16x8*)(Bs + rr * LDP + c8 * 8) = pb[i];
        }
        __syncthreads();

        if (step + 1 < KDIM / 32) load_pf((step + 1) * 32);

        f16x8 a[4], b[4];
        #pragma unroll
        for (int t = 0; t < 4; t++) {
            a[t] = *(const f16x8*)(As + (wrow * 64 + t * 16 + lr) * LDP + q * 8);
            b[t] = *(const f16x8*)(Bs + (wcol * 64 + t * 16 + lr) * LDP + q * 8);
        }
        #pragma unroll
        for (int ti = 0; ti < 4; ti++)
            #pragma unroll
            for (int tj = 0; tj < 4; tj++)
                acc[ti][tj] = __builtin_amdgcn_mfma_f32_16x16x32_f16(
                    a[ti], b[tj], acc[ti][tj], 0, 0, 0);
    }

    #pragma unroll
    for (int ti = 0; ti < 4; ti++) {
        #pragma unroll
        for (int tj = 0; tj < 4; tj++) {
            int col = col0 + wcol * 64 + tj * 16 + lr;
            if (col >= mpad) continue;
            bool valid = col < m;
            float bv = valid ? bias[col] : 0.0f;
            #pragma unroll
            for (int p = 0; p < 4; p++) {
                int row = row0 + wrow * 64 + ti * 16 + q * 4 + p;
                if (row < n) {
                    float v = valid ? (acc[ti][tj][p] + bv) : 0.0f;
                    Cb[(size_t)row * mpad + col] = (_Float16)v;
                }
            }
        }
    }
}

// ---------------- fp16 helpers ----------------

__device__ __forceinline__ float h2f(unsigned short u) {
    union { unsigned short s; _Float16 f; } t; t.s = u; return (float)t.f;
}

__device__ __forceinline__ void fma_h8(f32x4& a0, f32x4& a1, u16x8 v, float w) {
    #pragma unroll
    for (int i = 0; i < 4; i++) a0[i] += w * h2f(v[i]);
    #pragma unroll
    for (int i = 0; i < 4; i++) a1[i] += w * h2f(v[4 + i]);
}

// ---------------- SpMM L1: fp16 gather (stride 512) -> fp16 out (stride 512) --

__global__ __launch_bounds__(256) void spmm_f16_500_k(
    const int* __restrict__ row_ptr, const int* __restrict__ rowcnt,
    const int* __restrict__ col_s, const float* __restrict__ w_s,
    const float* __restrict__ dinv, const _Float16* __restrict__ hb,
    _Float16* __restrict__ outh)
{
    int r = blockIdx.x * 4 + (threadIdx.x >> 6);
    int lane = threadIdx.x & 63;
    if (r >= NN) return;

    const u16x8* h8 = (const u16x8*)hb;   // row stride = 64 vec8

    float d = dinv[r];
    f32x4 acc0 = {0.f, 0.f, 0.f, 0.f}, acc1 = {0.f, 0.f, 0.f, 0.f};
    fma_h8(acc0, acc1, h8[(size_t)r * 64 + lane], d * d);

    int beg = row_ptr[r], cnt = rowcnt[r];
    int j = 0;
    for (; j + 3 < cnt; j += 4) {
        int   c0 = col_s[beg + j],     c1 = col_s[beg + j + 1];
        int   c2 = col_s[beg + j + 2], c3 = col_s[beg + j + 3];
        float w0 = w_s[beg + j],       w1 = w_s[beg + j + 1];
        float w2 = w_s[beg + j + 2],   w3 = w_s[beg + j + 3];
        u16x8 v0 = h8[(size_t)c0 * 64 + lane];
        u16x8 v1 = h8[(size_t)c1 * 64 + lane];
        u16x8 v2 = h8[(size_t)c2 * 64 + lane];
        u16x8 v3 = h8[(size_t)c3 * 64 + lane];
        fma_h8(acc0, acc1, v0, w0);
        fma_h8(acc0, acc1, v1, w1);
        fma_h8(acc0, acc1, v2, w2);
        fma_h8(acc0, acc1, v3, w3);
    }
    for (; j < cnt; j++) {
        fma_h8(acc0, acc1, h8[(size_t)col_s[beg + j] * 64 + lane], w_s[beg + j]);
    }

    int f0 = lane * 8;
    f16x8 o;
    #pragma unroll
    for (int i = 0; i < 4; i++)
        o[i] = (_Float16)((f0 + i < HH1) ? tanhf(acc0[i]) : 0.0f);
    #pragma unroll
    for (int i = 0; i < 4; i++)
        o[4 + i] = (_Float16)((f0 + 4 + i < HH1) ? tanhf(acc1[i]) : 0.0f);
    __builtin_nontemporal_store(o, (f16x8*)(outh + (size_t)r * KD + f0));
}

// ---------------- SpMM L2: fp16 gather (stride 128) -> fp16 out (stride 128) --

__global__ __launch_bounds__(256) void spmm_f16_100_k(
    const int* __restrict__ row_ptr, const int* __restrict__ rowcnt,
    const int* __restrict__ col_s, const float* __restrict__ w_s,
    const float* __restrict__ dinv, const _Float16* __restrict__ hb,
    _Float16* __restrict__ outh)
{
    int r = blockIdx.x * 16 + (threadIdx.x >> 4);
    int lane = threadIdx.x & 15;
    if (r >= NN) return;

    const u16x8* h8 = (const u16x8*)hb;   // row stride = 16 vec8

    float d = dinv[r];
    f32x4 acc0 = {0.f, 0.f, 0.f, 0.f}, acc1 = {0.f, 0.f, 0.f, 0.f};
    fma_h8(acc0, acc1, h8[(size_t)r * 16 + lane], d * d);

    int beg = row_ptr[r], cnt = rowcnt[r];
    int j = 0;
    for (; j + 3 < cnt; j += 4) {
        int   c0 = col_s[beg + j],     c1 = col_s[beg + j + 1];
        int   c2 = col_s[beg + j + 2], c3 = col_s[beg + j + 3];
        float w0 = w_s[beg + j],       w1 = w_s[beg + j + 1];
        float w2 = w_s[beg + j + 2],   w3 = w_s[beg + j + 3];
        u16x8 v0 = h8[(size_t)c0 * 16 + lane];
        u16x8 v1 = h8[(size_t)c1 * 16 + lane];
        u16x8 v2 = h8[(size_t)c2 * 16 + lane];
        u16x8 v3 = h8[(size_t)c3 * 16 + lane];
        fma_h8(acc0, acc1, v0, w0);
        fma_h8(acc0, acc1, v1, w1);
        fma_h8(acc0, acc1, v2, w2);
        fma_h8(acc0, acc1, v3, w3);
    }
    for (; j < cnt; j++) {
        fma_h8(acc0, acc1, h8[(size_t)col_s[beg + j] * 16 + lane], w_s[beg + j]);
    }

    int f0 = lane * 8;
    f16x8 o;
    #pragma unroll
    for (int i = 0; i < 4; i++)
        o[i] = (_Float16)((f0 + i < HH2) ? tanhf(acc0[i]) : 0.0f);
    #pragma unroll
    for (int i = 0; i < 4; i++)
        o[4 + i] = (_Float16)((f0 + 4 + i < HH2) ? tanhf(acc1[i]) : 0.0f);
    __builtin_nontemporal_store(o, (f16x8*)(outh + (size_t)r * 128 + f0));
}

// ---------------- SpMM L3: fp16 gather (stride 16) -> fp32 out (stride 16) ----
// 2 lanes/row, 128 rows per 256-block. No activation.

__global__ __launch_bounds__(256) void spmm3h_k(
    const int* __restrict__ row_ptr, const int* __restrict__ rowcnt,
    const int* __restrict__ col_s, const float* __restrict__ w_s,
    const float* __restrict__ dinv, const _Float16* __restrict__ hb,
    float* __restrict__ out)
{
    int r = blockIdx.x * 128 + (threadIdx.x >> 1);
    int lane = threadIdx.x & 1;
    if (r >= NN) return;

    const u16x8* h8 = (const u16x8*)hb;   // row stride = 2 vec8

    float d = dinv[r];
    f32x4 acc0 = {0.f, 0.f, 0.f, 0.f}, acc1 = {0.f, 0.f, 0.f, 0.f};
    fma_h8(acc0, acc1, h8[(size_t)r * 2 + lane], d * d);

    int beg = row_ptr[r], cnt = rowcnt[r];
    int j = 0;
    for (; j + 3 < cnt; j += 4) {
        int   c0 = col_s[beg + j],     c1 = col_s[beg + j + 1];
        int   c2 = col_s[beg + j + 2], c3 = col_s[beg + j + 3];
        float w0 = w_s[beg + j],       w1 = w_s[beg + j + 1];
        float w2 = w_s[beg + j + 2],   w3 = w_s[beg + j + 3];
        u16x8 v0 = h8[(size_t)c0 * 2 + lane];
        u16x8 v1 = h8[(size_t)c1 * 2 + lane];
        u16x8 v2 = h8[(size_t)c2 * 2 + lane];
        u16x8 v3 = h8[(size_t)c3 * 2 + lane];
        fma_h8(acc0, acc1, v0, w0);
        fma_h8(acc0, acc1, v1, w1);
        fma_h8(acc0, acc1, v2, w2);
        fma_h8(acc0, acc1, v3, w3);
    }
    for (; j < cnt; j++) {
        fma_h8(acc0, acc1, h8[(size_t)col_s[beg + j] * 2 + lane], w_s[beg + j]);
    }

    float* o = out + (size_t)r * NC + lane * 8;
    __builtin_nontemporal_store(acc0, (f32x4*)o);
    __builtin_nontemporal_store(acc1, (f32x4*)(o + 4));
}

// final: tanh then softmax over 16 classes, one thread per row
__global__ void tanh_softmax_k(const float* __restrict__ in, float* __restrict__ out) {
    int r = blockIdx.x * blockDim.x + threadIdx.x;
    if (r >= NN) return;
    float v[NC];
    float mx = -1e30f;
    #pragma unroll
    for (int j = 0; j < NC; j++) {
        v[j] = tanhf(in[r * NC + j]);
        mx = fmaxf(mx, v[j]);
    }
    float s = 0.0f;
    #pragma unroll
    for (int j = 0; j < NC; j++) { v[j] = expf(v[j] - mx); s += v[j]; }
    float inv = 1.0f / s;
    #pragma unroll
    for (int j = 0; j < NC; j++) out[r * NC + j] = v[j] * inv;
}

// ---------------- launch ----------------

extern "C" void kernel_launch(void* const* d_in, const int* in_sizes, int n_in,
                              void* d_out, int out_size, void* d_ws, size_t ws_size,
                              hipStream_t stream)
{
    const float* x  = (const float*)d_in[0];
    const int*   ei = (const int*)d_in[1];
    const float* W1 = (const float*)d_in[2];
    const float* b1 = (const float*)d_in[3];
    const float* W2 = (const float*)d_in[4];
    const float* b2 = (const float*)d_in[5];
    const float* W3 = (const float*)d_in[6];
    const float* b3 = (const float*)d_in[7];
    float* out = (float*)d_out;

    const int* rows = ei;
    const int* cols = ei + NE;

    char* p = (char*)d_ws;
    float*     dinv    = (float*)p;     p += (size_t)NN * 4;
    int*       rowcnt  = (int*)p;       p += (size_t)NN * 4;
    int*       row_ptr = (int*)p;       p += (size_t)NN * 4;
    int*       fill    = (int*)p;       p += (size_t)NN * 4;
    int*       excl    = (int*)p;       p += (size_t)NN * 4;
    int*       bsum    = (int*)p;       p += (size_t)256 * 4;
    int*       col_s   = (int*)p;       p += (size_t)NE * 4;
    float*     w_s     = (float*)p;     p += (size_t)NE * 4;
    float*     B3      = (float*)p;     p += (size_t)NN * NC * 4;   // SpMM3 out
    _Float16*  A1h     = (_Float16*)p;  p += (size_t)NN * KD * 2;   // GEMM1 out
    _Float16*  h1h     = (_Float16*)p;  p += (size_t)NN * KD * 2;   // SpMM1 out
    _Float16*  A2h     = (_Float16*)p;  p += (size_t)NN * 128 * 2;  // GEMM2 out
    _Float16*  h2h     = (_Float16*)p;  p += (size_t)NN * 128 * 2;  // SpMM2 out
    _Float16*  A3h     = (_Float16*)p;  p += (size_t)NN * NC * 2;   // GEMM3 out
    _Float16*  Wt1     = (_Float16*)p;  p += (size_t)R1 * 2;
    _Float16*  Wt2     = (_Float16*)p;  p += (size_t)R2 * 2;
    _Float16*  Wt3     = (_Float16*)p;  p += (size_t)R3 * 2;

    const int T = 256;
    const int NB = (NN + 1023) / 1024;   // 49

    // ---- preprocessing
    wconv3_k<<<(R1 + R2 + R3) / 256, T, 0, stream>>>(W1, W2, W3, Wt1, Wt2, Wt3);
    zero2_k<<<(NN + T - 1) / T, T, 0, stream>>>(rowcnt, fill);
    hist_k<<<(NE + T - 1) / T, T, 0, stream>>>(rows, rowcnt);
    dinv_k<<<(NN + T - 1) / T, T, 0, stream>>>(rowcnt, dinv);
    scan1_k<<<NB, 1024, 0, stream>>>(rowcnt, excl, bsum);
    scan2_k<<<1, 64, 0, stream>>>(bsum, NB);
    scan3_k<<<(NN + T - 1) / T, T, 0, stream>>>(excl, bsum, row_ptr);
    scatter_k<<<(NE + T - 1) / T, T, 0, stream>>>(rows, cols, dinv, row_ptr, fill,
                                                  col_s, w_s);

    // ---- layer 1: 512 -> 500
    {
        dim3 g((NN + 127) / 128, 4);
        gemm_f16_k<0, 512><<<g, T, 0, stream>>>(x, Wt1, b1, A1h, KD, NN, HH1);
        spmm_f16_500_k<<<(NN + 3) / 4, T, 0, stream>>>(row_ptr, rowcnt, col_s, w_s,
                                                       dinv, A1h, h1h);
    }
    // ---- layer 2: 500 -> 100
    {
        dim3 g((NN + 127) / 128, 1);
        gemm_f16_k<1, 512><<<g, T, 0, stream>>>(h1h, Wt2, b2, A2h, 128, NN, HH2);
        spmm_f16_100_k<<<(NN + 15) / 16, T, 0, stream>>>(row_ptr, rowcnt, col_s, w_s,
                                                         dinv, A2h, h2h);
    }
    // ---- layer 3: 100 -> 16
    {
        dim3 g((NN + 127) / 128, 1);
        gemm_f16_k<1, 128><<<g, T, 0, stream>>>(h2h, Wt3, b3, A3h, NC, NN, NC);
        spmm3h_k<<<(NN + 127) / 128, T, 0, stream>>>(row_ptr, rowcnt, col_s, w_s,
                                                     dinv, A3h, B3);
        tanh_softmax_k<<<(NN + T - 1) / T, T, 0, stream>>>(B3, out);
    }
}